// Round 10
// baseline (36645.300 us; speedup 1.0000x reference)
//
#include <hip/hip_runtime.h>
#include <stdint.h>

// TLSTM: batch-1 LSTM, T=16384 steps, IN=512, H=1024, OUT=64.
// Persistent-kernel design: 256 WGs (one per CU). WG b owns h-elements
// {4b..4b+3}; wave w owns element 4b+w and computes all 4 gate rows for
// it; weights live in registers. Cross-WG h exchange per step through a
// tagged 64-bit {step, value} word per h-element, double-buffered by
// step parity.
//
// Experiment ledger:
//   R1: coalesced 2x16B poll sweeps           35.0 -> 29.0 ms
//   R2: pipelined vmcnt poll                  -> 90+ ms (foreign loads
//       in the poll's counted-vmcnt window)
//   R3: 4B words                              -> 36.5 ms
//   R4: s_sleep-paced poll                    -> 29.0 == R1 (consumer
//       pacing is FREE; poll latency-bound)
//   R5: A/B counted-vmcnt(2) poll             -> crashed; abandoned
//   R6: x-staging off pre-poll path           -> 67.6 ms (pre-poll
//       x-load delay is LOAD-BEARING for first-sample timing)
//   R7: 8x replica + contiguous sweep         -> 31.1 ms (consumer-side
//       per-line spreading: NULL on detect latency)
//   R8: x-projection moved pre-poll           -> 27.6 ms [predicted]
//   R9: DPP reduce replaces shfl butterfly    -> 24.1 ms [predicted+]
// Synthesis: consumer request rate/pattern is irrelevant (R4,R7);
// serial compute around the rendezvous is addressable (R8,R9); R3's
// regression must therefore have been STORE-side (more producers per
// sector). Current layout: 8 producer waves (8 CUs) store into each
// 64B line every step -> 8-deep same-line store serialization at the
// owning L2 sector, directly on the store->visible critical edge.
// R10 (this): spread the exchange to ONE producer word per 64B line
// (hbuf = [2][1024] lines, 128 KB). Producer: single uncontended 8B
// store. Consumer: 4x dwordx2 sc0 sc1 at stride 64B (thread's 4 lines
// are private within the WG -> per-line rate unchanged; total consumer
// requests 8x = proven free). All else byte-identical to R9.

typedef unsigned long long u64;
typedef uint32_t u32x2 __attribute__((ext_vector_type(2)));

#define T_STEPS 16384
#define IN_DIM  512
#define H_DIM   1024
#define OUT_DIM 64
#define NWG     256
#define LINE_U64 8   // one 64B line per h-element

__device__ __forceinline__ float sigf(float x) {
    return 1.0f / (1.0f + __expf(-x));
}
__device__ __forceinline__ float tanh_fast(float x) {
    // tanh(x) = 2*sigmoid(2x) - 1 ; |err| ~1e-7 rel with __expf
    return 2.0f / (1.0f + __expf(-2.0f * x)) - 1.0f;
}

__global__ __launch_bounds__(256, 1) void lstm_seq(
    const float* __restrict__ X,
    const float* __restrict__ W_ih,
    const float* __restrict__ W_hh,
    const float* __restrict__ b_ih,
    const float* __restrict__ b_hh,
    u64* __restrict__ hbuf)   // [2][H_DIM] lines: elem j at word j*8
{
    const int b    = blockIdx.x;      // 0..255
    const int tid  = threadIdx.x;     // 0..255
    const int w    = tid >> 6;        // wave id == owned element index j
    const int lane = tid & 63;
    const int elem = 4 * b + w;       // global h index this wave produces

    __shared__ float h_lds[2][H_DIM];

    // ---- one-time: weights into registers ----
    float4 wh[4][4];   // [gate][chunk]  over H_DIM=1024
    float4 wx[4][2];   // [gate][chunk]  over IN_DIM=512
    float  bias_g[4];
    #pragma unroll
    for (int g = 0; g < 4; ++g) {
        const int row = g * H_DIM + elem;
        #pragma unroll
        for (int c = 0; c < 4; ++c)
            wh[g][c] = *(const float4*)(W_hh + (size_t)row * H_DIM + (c * 256 + lane * 4));
        #pragma unroll
        for (int c = 0; c < 2; ++c)
            wx[g][c] = *(const float4*)(W_ih + (size_t)row * IN_DIM + (c * 256 + lane * 4));
        bias_g[g] = b_ih[row] + b_hh[row];
    }

    // per-thread poll bases: thread tid owns elements {4tid..4tid+3} =
    // 4 consecutive 64B lines starting at word (p*H_DIM + 4*tid)*8
    const u64* pollbase0 = hbuf + (size_t)(tid * 4) * LINE_U64;
    const u64* pollbase1 = hbuf + (size_t)(H_DIM + tid * 4) * LINE_U64;

    float c_state = 0.0f;   // cell state for `elem` (valid on lane 63 only)

    for (int t = 0; t < T_STEPS; ++t) {
        const int p = t & 1;

        // ---- per-lane x fragments + x-gate partials, BEFORE the poll ----
        // (R8: load-bearing pre-poll delay + off the post-barrier path)
        const float4 xv0 = *(const float4*)(X + (size_t)t * IN_DIM + lane * 4);
        const float4 xv1 = *(const float4*)(X + (size_t)t * IN_DIM + 256 + lane * 4);
        float acc0, acc1, acc2, acc3;
        acc0 = wx[0][0].x*xv0.x + wx[0][0].y*xv0.y + wx[0][0].z*xv0.z + wx[0][0].w*xv0.w
             + wx[0][1].x*xv1.x + wx[0][1].y*xv1.y + wx[0][1].z*xv1.z + wx[0][1].w*xv1.w;
        acc1 = wx[1][0].x*xv0.x + wx[1][0].y*xv0.y + wx[1][0].z*xv0.z + wx[1][0].w*xv0.w
             + wx[1][1].x*xv1.x + wx[1][1].y*xv1.y + wx[1][1].z*xv1.z + wx[1][1].w*xv1.w;
        acc2 = wx[2][0].x*xv0.x + wx[2][0].y*xv0.y + wx[2][0].z*xv0.z + wx[2][0].w*xv0.w
             + wx[2][1].x*xv1.x + wx[2][1].y*xv1.y + wx[2][1].z*xv1.z + wx[2][1].w*xv1.w;
        acc3 = wx[3][0].x*xv0.x + wx[3][0].y*xv0.y + wx[3][0].z*xv0.z + wx[3][0].w*xv0.w
             + wx[3][1].x*xv1.x + wx[3][1].y*xv1.y + wx[3][1].z*xv1.z + wx[3][1].w*xv1.w;
        asm volatile("" : "+v"(acc0), "+v"(acc1), "+v"(acc2), "+v"(acc3));

        // ---- poll h[t]: 4 scattered 8B tagged words, one per 64B line ----
        {
            const u64* src = p ? pollbase1 : pollbase0;
            const uint32_t tu = (uint32_t)t;
            u32x2 a, b2, c2, d2;
            for (;;) {
                asm volatile(
                    "global_load_dwordx2 %0, %4, off sc0 sc1\n\t"
                    "global_load_dwordx2 %1, %4, off offset:64 sc0 sc1\n\t"
                    "global_load_dwordx2 %2, %4, off offset:128 sc0 sc1\n\t"
                    "global_load_dwordx2 %3, %4, off offset:192 sc0 sc1\n\t"
                    "s_waitcnt vmcnt(0)"
                    : "=&v"(a), "=&v"(b2), "=&v"(c2), "=&v"(d2)
                    : "v"(src)
                    : "memory");
                // each pair: [val, tag]
                if ((((a[1] ^ tu) | (b2[1] ^ tu)) |
                     ((c2[1] ^ tu) | (d2[1] ^ tu))) == 0u)
                    break;
            }
            h_lds[p][tid * 4 + 0] = __uint_as_float(a[0]);
            h_lds[p][tid * 4 + 1] = __uint_as_float(b2[0]);
            h_lds[p][tid * 4 + 2] = __uint_as_float(c2[0]);
            h_lds[p][tid * 4 + 3] = __uint_as_float(d2[0]);
        }
        __syncthreads();   // single barrier per step: h staging complete

        // ---- 4 gate dot-products over h for `elem` (x already folded) ----
        const float4* h4 = (const float4*)(&h_lds[p][0]);
        #pragma unroll
        for (int c = 0; c < 4; ++c) {
            const float4 hv = h4[c * 64 + lane];
            acc0 += wh[0][c].x*hv.x + wh[0][c].y*hv.y + wh[0][c].z*hv.z + wh[0][c].w*hv.w;
            acc1 += wh[1][c].x*hv.x + wh[1][c].y*hv.y + wh[1][c].z*hv.z + wh[1][c].w*hv.w;
            acc2 += wh[2][c].x*hv.x + wh[2][c].y*hv.y + wh[2][c].z*hv.z + wh[2][c].w*hv.w;
            acc3 += wh[3][c].x*hv.x + wh[3][c].y*hv.y + wh[3][c].z*hv.z + wh[3][c].w*hv.w;
        }

        // ---- DPP wave reduction: 4 interleaved chains, sum -> lane 63 ----
        asm volatile(
            "v_add_f32_dpp %0, %0, %0 row_shr:1 row_mask:0xf bank_mask:0xf bound_ctrl:0\n\t"
            "v_add_f32_dpp %1, %1, %1 row_shr:1 row_mask:0xf bank_mask:0xf bound_ctrl:0\n\t"
            "v_add_f32_dpp %2, %2, %2 row_shr:1 row_mask:0xf bank_mask:0xf bound_ctrl:0\n\t"
            "v_add_f32_dpp %3, %3, %3 row_shr:1 row_mask:0xf bank_mask:0xf bound_ctrl:0\n\t"
            "v_add_f32_dpp %0, %0, %0 row_shr:2 row_mask:0xf bank_mask:0xf bound_ctrl:0\n\t"
            "v_add_f32_dpp %1, %1, %1 row_shr:2 row_mask:0xf bank_mask:0xf bound_ctrl:0\n\t"
            "v_add_f32_dpp %2, %2, %2 row_shr:2 row_mask:0xf bank_mask:0xf bound_ctrl:0\n\t"
            "v_add_f32_dpp %3, %3, %3 row_shr:2 row_mask:0xf bank_mask:0xf bound_ctrl:0\n\t"
            "v_add_f32_dpp %0, %0, %0 row_shr:4 row_mask:0xf bank_mask:0xf bound_ctrl:0\n\t"
            "v_add_f32_dpp %1, %1, %1 row_shr:4 row_mask:0xf bank_mask:0xf bound_ctrl:0\n\t"
            "v_add_f32_dpp %2, %2, %2 row_shr:4 row_mask:0xf bank_mask:0xf bound_ctrl:0\n\t"
            "v_add_f32_dpp %3, %3, %3 row_shr:4 row_mask:0xf bank_mask:0xf bound_ctrl:0\n\t"
            "v_add_f32_dpp %0, %0, %0 row_shr:8 row_mask:0xf bank_mask:0xf bound_ctrl:0\n\t"
            "v_add_f32_dpp %1, %1, %1 row_shr:8 row_mask:0xf bank_mask:0xf bound_ctrl:0\n\t"
            "v_add_f32_dpp %2, %2, %2 row_shr:8 row_mask:0xf bank_mask:0xf bound_ctrl:0\n\t"
            "v_add_f32_dpp %3, %3, %3 row_shr:8 row_mask:0xf bank_mask:0xf bound_ctrl:0\n\t"
            "v_add_f32_dpp %0, %0, %0 row_bcast:15 row_mask:0xa bank_mask:0xf bound_ctrl:0\n\t"
            "v_add_f32_dpp %1, %1, %1 row_bcast:15 row_mask:0xa bank_mask:0xf bound_ctrl:0\n\t"
            "v_add_f32_dpp %2, %2, %2 row_bcast:15 row_mask:0xa bank_mask:0xf bound_ctrl:0\n\t"
            "v_add_f32_dpp %3, %3, %3 row_bcast:15 row_mask:0xa bank_mask:0xf bound_ctrl:0\n\t"
            "v_add_f32_dpp %0, %0, %0 row_bcast:31 row_mask:0xc bank_mask:0xf bound_ctrl:0\n\t"
            "v_add_f32_dpp %1, %1, %1 row_bcast:31 row_mask:0xc bank_mask:0xf bound_ctrl:0\n\t"
            "v_add_f32_dpp %2, %2, %2 row_bcast:31 row_mask:0xc bank_mask:0xf bound_ctrl:0\n\t"
            "v_add_f32_dpp %3, %3, %3 row_bcast:31 row_mask:0xc bank_mask:0xf bound_ctrl:0"
            : "+v"(acc0), "+v"(acc1), "+v"(acc2), "+v"(acc3));

        // ---- combine: only lane 63 holds the true sums ----
        const float ii = sigf(acc0 + bias_g[0]);
        const float ff = sigf(acc1 + bias_g[1]);
        const float gg = tanh_fast(acc2 + bias_g[2]);
        const float oo = sigf(acc3 + bias_g[3]);
        const float cn = ff * c_state + ii * gg;
        c_state = cn;
        const float hn = oo * tanh_fast(cn);

        if (lane == 63) {
            const u64 word = ((u64)(unsigned)(t + 1) << 32)
                           | (u64)__float_as_uint(hn);
            // one producer per 64B line: no same-line store contention
            __hip_atomic_store(
                hbuf + (size_t)(((t + 1) & 1) * H_DIM + elem) * LINE_U64,
                word, __ATOMIC_RELAXED, __HIP_MEMORY_SCOPE_AGENT);
        }
        // No second barrier needed: next-step staging writes parity (t+1)&1,
        // disjoint from this step's reads; tag protocol covers parity reuse.
    }
}

__global__ __launch_bounds__(256, 1) void lstm_head(
    const u64* __restrict__ hbuf,
    const float* __restrict__ W_lin,
    const float* __restrict__ b_lin,
    float* __restrict__ out)
{
    const int tid  = threadIdx.x;
    const int o    = tid >> 2;       // output index, 4 threads per output
    const int part = tid & 3;
    const u64* src = hbuf + (size_t)(T_STEPS & 1) * H_DIM * LINE_U64;

    float sum = 0.f;
    const int k0 = part * 256;
    for (int k = k0; k < k0 + 256; k += 4) {
        const float4 wv = *(const float4*)(W_lin + (size_t)o * H_DIM + k);
        sum += wv.x * __uint_as_float((unsigned)src[(size_t)(k + 0) * LINE_U64])
             + wv.y * __uint_as_float((unsigned)src[(size_t)(k + 1) * LINE_U64])
             + wv.z * __uint_as_float((unsigned)src[(size_t)(k + 2) * LINE_U64])
             + wv.w * __uint_as_float((unsigned)src[(size_t)(k + 3) * LINE_U64]);
    }
    sum += __shfl_xor(sum, 1);
    sum += __shfl_xor(sum, 2);
    if (part == 0)
        out[o] = 1.0f / (1.0f + __expf(-(sum + b_lin[o])));
}

extern "C" void kernel_launch(void* const* d_in, const int* in_sizes, int n_in,
                              void* d_out, int out_size, void* d_ws, size_t ws_size,
                              hipStream_t stream) {
    const float* X     = (const float*)d_in[0];
    // d_in[1] Mask, d_in[2] Delta, d_in[3] dt: unused by the forward pass
    const float* W_ih  = (const float*)d_in[4];
    const float* W_hh  = (const float*)d_in[5];
    const float* b_ih  = (const float*)d_in[6];
    const float* b_hh  = (const float*)d_in[7];
    const float* W_lin = (const float*)d_in[8];
    const float* b_lin = (const float*)d_in[9];
    float* out = (float*)d_out;

    u64* hbuf = (u64*)d_ws;   // 2 * 1024 * 64B = 128 KiB used

    // init: both parity buffers = {tag=0, h=0.0f} (all zero bytes)
    hipMemsetAsync(hbuf, 0, 2 * H_DIM * LINE_U64 * sizeof(u64), stream);

    lstm_seq<<<NWG, 256, 0, stream>>>(X, W_ih, W_hh, b_ih, b_hh, hbuf);
    lstm_head<<<1, 256, 0, stream>>>(hbuf, W_lin, b_lin, out);
}

// Round 11
// 22270.810 us; speedup vs baseline: 1.6454x; 1.6454x over previous
//
#include <hip/hip_runtime.h>
#include <stdint.h>

// TLSTM: batch-1 LSTM, T=16384 steps, IN=512, H=1024, OUT=64.
// Persistent-kernel design: 256 WGs (one per CU). WG b owns h-elements
// {4b..4b+3}; wave w owns element 4b+w and computes all 4 gate rows for
// it; weights live in registers. Cross-WG h exchange per step through a
// tagged 64-bit {step, value} word per h-element (dense [2][1024] u64 =
// 16 KB), double-buffered by step parity.
//
// Experiment ledger:
//   R1: coalesced 2x16B poll sweeps           35.0 -> 29.0 ms
//   R2: pipelined vmcnt poll                  -> 90+ ms
//   R3: 4B words                              -> 36.5 ms
//   R4: s_sleep-paced poll                    -> 29.0 == R1
//   R5: A/B counted-vmcnt(2) poll             -> crashed; abandoned
//   R6: x-staging off pre-poll path           -> 67.6 ms (pre-poll
//       x-load delay is LOAD-BEARING)
//   R7: 8x replica spread                     -> 31.1 ms (null + fanout)
//   R8: x-projection pre-poll                 -> 27.6 ms [predicted]
//   R9: DPP reduce                            -> 24.1 ms [predicted+]
//   R10: one word per 64B line                -> 36.6 ms, FETCH 6.5x
//        => consumer LINES-PER-SWEEP is the cost axis; R1/R9's dense
//        32B/thread layout is the verified optimum. Layout closed.
// Synthesis: the rendezvous (~2500cy) is insensitive to every knob
// tested; only serial compute around it pays (R8, R9). R11 = R9 +
// three post-barrier trims:
//   (a) v_pk_fma_f32 packed FMAs (k-pairs; natural .xy/.zw pairing,
//       f32x2 accumulators, 1 horizontal add per gate pre-reduce):
//       h-path 64->32 VALU issues, x-path 32->16.
//   (b) own-chunk-in-regs: thread 64w+l polls exactly chunk c=w's
//       elements 256w+4l+{0..3} -> keep in regs, skip 1 of 4
//       ds_read_b128. Weight slots rotated at init (slot j = chunk
//       (w+j)&3) so register indices stay compile-time.
//   (c) staging via one ds_write_b128 instead of 4 ds_write_b32.

typedef unsigned long long u64;
typedef uint32_t u32x4 __attribute__((ext_vector_type(4)));
typedef float v2f __attribute__((ext_vector_type(2)));
typedef float v4f __attribute__((ext_vector_type(4)));

#define T_STEPS 16384
#define IN_DIM  512
#define H_DIM   1024
#define OUT_DIM 64
#define NWG     256

#define PK_MUL(D, A, B) \
    asm("v_pk_mul_f32 %0, %1, %2" : "=v"(D) : "v"(A), "v"(B))
#define PK_FMA(D, A, B) \
    asm("v_pk_fma_f32 %0, %1, %2, %0" : "+v"(D) : "v"(A), "v"(B))

__device__ __forceinline__ float sigf(float x) {
    return 1.0f / (1.0f + __expf(-x));
}
__device__ __forceinline__ float tanh_fast(float x) {
    // tanh(x) = 2*sigmoid(2x) - 1 ; |err| ~1e-7 rel with __expf
    return 2.0f / (1.0f + __expf(-2.0f * x)) - 1.0f;
}

__global__ __launch_bounds__(256, 1) void lstm_seq(
    const float* __restrict__ X,
    const float* __restrict__ W_ih,
    const float* __restrict__ W_hh,
    const float* __restrict__ b_ih,
    const float* __restrict__ b_hh,
    u64* __restrict__ hbuf)   // [2][H_DIM] tagged words in d_ws
{
    const int b    = blockIdx.x;      // 0..255
    const int tid  = threadIdx.x;     // 0..255
    const int w    = tid >> 6;        // wave id == owned element index j
    const int lane = tid & 63;
    const int elem = 4 * b + w;       // global h index this wave produces

    __shared__ __align__(16) float h_lds[2][H_DIM];

    // ---- one-time: weights into registers, packed as k-pairs ----
    // whp[slot][gate][pair]: slot j holds chunk c=(w+j)&3 (rotation keeps
    // all register indices compile-time while slot 0 == own polled chunk).
    v2f whp[4][4][2];
    v2f wxp[4][2][2];   // [gate][chunk][pair] over IN_DIM=512
    float bias_g[4];
    #pragma unroll
    for (int j = 0; j < 4; ++j) {
        const int c = (w + j) & 3;
        #pragma unroll
        for (int g = 0; g < 4; ++g) {
            const float* base = W_hh + (size_t)(g * H_DIM + elem) * H_DIM
                              + (c * 256 + lane * 4);
            whp[j][g][0] = *(const v2f*)(base);
            whp[j][g][1] = *(const v2f*)(base + 2);
        }
    }
    #pragma unroll
    for (int g = 0; g < 4; ++g) {
        const int row = g * H_DIM + elem;
        #pragma unroll
        for (int c = 0; c < 2; ++c) {
            const float* base = W_ih + (size_t)row * IN_DIM + (c * 256 + lane * 4);
            wxp[g][c][0] = *(const v2f*)(base);
            wxp[g][c][1] = *(const v2f*)(base + 2);
        }
        bias_g[g] = b_ih[row] + b_hh[row];
    }

    // per-thread poll bases for the two parity buffers (4 tagged words = 32B)
    const uint32_t* poll0 = (const uint32_t*)(hbuf + (size_t)tid * 4);
    const uint32_t* poll1 = (const uint32_t*)(hbuf + (size_t)H_DIM + (size_t)tid * 4);

    float c_state = 0.0f;   // cell state for `elem` (valid on lane 63 only)

    for (int t = 0; t < T_STEPS; ++t) {
        const int p = t & 1;

        // ---- per-lane x fragments + packed x-gate partials, pre-poll ----
        // (R8: load-bearing pre-poll delay + off the post-barrier path)
        const v4f xv0 = *(const v4f*)(X + (size_t)t * IN_DIM + lane * 4);
        const v4f xv1 = *(const v4f*)(X + (size_t)t * IN_DIM + 256 + lane * 4);
        const v2f xp0 = __builtin_shufflevector(xv0, xv0, 0, 1);
        const v2f xp1 = __builtin_shufflevector(xv0, xv0, 2, 3);
        const v2f xp2 = __builtin_shufflevector(xv1, xv1, 0, 1);
        const v2f xp3 = __builtin_shufflevector(xv1, xv1, 2, 3);
        v2f ap0, ap1, ap2, ap3;   // per-gate packed (even-k, odd-k) partials
        PK_MUL(ap0, wxp[0][0][0], xp0); PK_MUL(ap1, wxp[1][0][0], xp0);
        PK_MUL(ap2, wxp[2][0][0], xp0); PK_MUL(ap3, wxp[3][0][0], xp0);
        PK_FMA(ap0, wxp[0][0][1], xp1); PK_FMA(ap1, wxp[1][0][1], xp1);
        PK_FMA(ap2, wxp[2][0][1], xp1); PK_FMA(ap3, wxp[3][0][1], xp1);
        PK_FMA(ap0, wxp[0][1][0], xp2); PK_FMA(ap1, wxp[1][1][0], xp2);
        PK_FMA(ap2, wxp[2][1][0], xp2); PK_FMA(ap3, wxp[3][1][0], xp2);
        PK_FMA(ap0, wxp[0][1][1], xp3); PK_FMA(ap1, wxp[1][1][1], xp3);
        PK_FMA(ap2, wxp[2][1][1], xp3); PK_FMA(ap3, wxp[3][1][1], xp3);
        // Pin partials as materialized pre-poll (no sinking past the poll).
        asm volatile("" : "+v"(ap0), "+v"(ap1), "+v"(ap2), "+v"(ap3));

        // ---- poll h[t]: R1/R9-exact single-slot poll ----
        u32x4 a, b4;
        {
            const uint32_t* src = p ? poll1 : poll0;
            const uint32_t tu = (uint32_t)t;
            for (;;) {
                asm volatile(
                    "global_load_dwordx4 %0, %2, off sc0 sc1\n\t"
                    "global_load_dwordx4 %1, %2, off offset:16 sc0 sc1\n\t"
                    "s_waitcnt vmcnt(0)"
                    : "=&v"(a), "=&v"(b4)
                    : "v"(src)
                    : "memory");
                if ((((a[1] ^ tu) | (a[3] ^ tu)) | ((b4[1] ^ tu) | (b4[3] ^ tu))) == 0u)
                    break;
            }
        }
        // own 4 elements (== chunk c=w for this lane) kept in regs; one
        // packed ds_write_b128 stages them for the other waves.
        v4f hw;
        hw[0] = __uint_as_float(a[0]);
        hw[1] = __uint_as_float(a[2]);
        hw[2] = __uint_as_float(b4[0]);
        hw[3] = __uint_as_float(b4[2]);
        *(v4f*)(&h_lds[p][tid * 4]) = hw;
        __syncthreads();   // single barrier per step: h staging complete

        // ---- packed h-gate FMAs: slot 0 from regs, slots 1..3 from LDS ----
        {
            const v2f h01 = __builtin_shufflevector(hw, hw, 0, 1);
            const v2f h23 = __builtin_shufflevector(hw, hw, 2, 3);
            PK_FMA(ap0, whp[0][0][0], h01); PK_FMA(ap1, whp[0][1][0], h01);
            PK_FMA(ap2, whp[0][2][0], h01); PK_FMA(ap3, whp[0][3][0], h01);
            PK_FMA(ap0, whp[0][0][1], h23); PK_FMA(ap1, whp[0][1][1], h23);
            PK_FMA(ap2, whp[0][2][1], h23); PK_FMA(ap3, whp[0][3][1], h23);
        }
        #pragma unroll
        for (int j = 1; j < 4; ++j) {
            const int c = (w + j) & 3;
            const v4f hv = *(const v4f*)(&h_lds[p][c * 256 + lane * 4]);
            const v2f h01 = __builtin_shufflevector(hv, hv, 0, 1);
            const v2f h23 = __builtin_shufflevector(hv, hv, 2, 3);
            PK_FMA(ap0, whp[j][0][0], h01); PK_FMA(ap1, whp[j][1][0], h01);
            PK_FMA(ap2, whp[j][2][0], h01); PK_FMA(ap3, whp[j][3][0], h01);
            PK_FMA(ap0, whp[j][0][1], h23); PK_FMA(ap1, whp[j][1][1], h23);
            PK_FMA(ap2, whp[j][2][1], h23); PK_FMA(ap3, whp[j][3][1], h23);
        }

        // fold packed halves, then DPP wave reduction -> lane 63
        float acc0 = ap0[0] + ap0[1];
        float acc1 = ap1[0] + ap1[1];
        float acc2 = ap2[0] + ap2[1];
        float acc3 = ap3[0] + ap3[1];
        asm volatile(
            "v_add_f32_dpp %0, %0, %0 row_shr:1 row_mask:0xf bank_mask:0xf bound_ctrl:0\n\t"
            "v_add_f32_dpp %1, %1, %1 row_shr:1 row_mask:0xf bank_mask:0xf bound_ctrl:0\n\t"
            "v_add_f32_dpp %2, %2, %2 row_shr:1 row_mask:0xf bank_mask:0xf bound_ctrl:0\n\t"
            "v_add_f32_dpp %3, %3, %3 row_shr:1 row_mask:0xf bank_mask:0xf bound_ctrl:0\n\t"
            "v_add_f32_dpp %0, %0, %0 row_shr:2 row_mask:0xf bank_mask:0xf bound_ctrl:0\n\t"
            "v_add_f32_dpp %1, %1, %1 row_shr:2 row_mask:0xf bank_mask:0xf bound_ctrl:0\n\t"
            "v_add_f32_dpp %2, %2, %2 row_shr:2 row_mask:0xf bank_mask:0xf bound_ctrl:0\n\t"
            "v_add_f32_dpp %3, %3, %3 row_shr:2 row_mask:0xf bank_mask:0xf bound_ctrl:0\n\t"
            "v_add_f32_dpp %0, %0, %0 row_shr:4 row_mask:0xf bank_mask:0xf bound_ctrl:0\n\t"
            "v_add_f32_dpp %1, %1, %1 row_shr:4 row_mask:0xf bank_mask:0xf bound_ctrl:0\n\t"
            "v_add_f32_dpp %2, %2, %2 row_shr:4 row_mask:0xf bank_mask:0xf bound_ctrl:0\n\t"
            "v_add_f32_dpp %3, %3, %3 row_shr:4 row_mask:0xf bank_mask:0xf bound_ctrl:0\n\t"
            "v_add_f32_dpp %0, %0, %0 row_shr:8 row_mask:0xf bank_mask:0xf bound_ctrl:0\n\t"
            "v_add_f32_dpp %1, %1, %1 row_shr:8 row_mask:0xf bank_mask:0xf bound_ctrl:0\n\t"
            "v_add_f32_dpp %2, %2, %2 row_shr:8 row_mask:0xf bank_mask:0xf bound_ctrl:0\n\t"
            "v_add_f32_dpp %3, %3, %3 row_shr:8 row_mask:0xf bank_mask:0xf bound_ctrl:0\n\t"
            "v_add_f32_dpp %0, %0, %0 row_bcast:15 row_mask:0xa bank_mask:0xf bound_ctrl:0\n\t"
            "v_add_f32_dpp %1, %1, %1 row_bcast:15 row_mask:0xa bank_mask:0xf bound_ctrl:0\n\t"
            "v_add_f32_dpp %2, %2, %2 row_bcast:15 row_mask:0xa bank_mask:0xf bound_ctrl:0\n\t"
            "v_add_f32_dpp %3, %3, %3 row_bcast:15 row_mask:0xa bank_mask:0xf bound_ctrl:0\n\t"
            "v_add_f32_dpp %0, %0, %0 row_bcast:31 row_mask:0xc bank_mask:0xf bound_ctrl:0\n\t"
            "v_add_f32_dpp %1, %1, %1 row_bcast:31 row_mask:0xc bank_mask:0xf bound_ctrl:0\n\t"
            "v_add_f32_dpp %2, %2, %2 row_bcast:31 row_mask:0xc bank_mask:0xf bound_ctrl:0\n\t"
            "v_add_f32_dpp %3, %3, %3 row_bcast:31 row_mask:0xc bank_mask:0xf bound_ctrl:0"
            : "+v"(acc0), "+v"(acc1), "+v"(acc2), "+v"(acc3));

        // ---- combine: only lane 63 holds the true sums ----
        const float ii = sigf(acc0 + bias_g[0]);
        const float ff = sigf(acc1 + bias_g[1]);
        const float gg = tanh_fast(acc2 + bias_g[2]);
        const float oo = sigf(acc3 + bias_g[3]);
        const float cn = ff * c_state + ii * gg;
        c_state = cn;
        const float hn = oo * tanh_fast(cn);

        if (lane == 63) {
            const u64 word = ((u64)(unsigned)(t + 1) << 32)
                           | (u64)__float_as_uint(hn);
            __hip_atomic_store(hbuf + (size_t)((t + 1) & 1) * H_DIM + elem,
                               word, __ATOMIC_RELAXED, __HIP_MEMORY_SCOPE_AGENT);
        }
        // No second barrier needed: next-step staging writes parity (t+1)&1,
        // disjoint from this step's reads; tag protocol covers parity reuse.
    }
}

__global__ __launch_bounds__(256, 1) void lstm_head(
    const u64* __restrict__ hbuf,
    const float* __restrict__ W_lin,
    const float* __restrict__ b_lin,
    float* __restrict__ out)
{
    const int tid  = threadIdx.x;
    const int o    = tid >> 2;       // output index, 4 threads per output
    const int part = tid & 3;
    const u64* src = hbuf + (size_t)(T_STEPS & 1) * H_DIM;  // buf[0]: tag T

    float sum = 0.f;
    const int k0 = part * 256;
    for (int k = k0; k < k0 + 256; k += 4) {
        const float4 wv = *(const float4*)(W_lin + (size_t)o * H_DIM + k);
        sum += wv.x * __uint_as_float((unsigned)src[k + 0])
             + wv.y * __uint_as_float((unsigned)src[k + 1])
             + wv.z * __uint_as_float((unsigned)src[k + 2])
             + wv.w * __uint_as_float((unsigned)src[k + 3]);
    }
    sum += __shfl_xor(sum, 1);
    sum += __shfl_xor(sum, 2);
    if (part == 0)
        out[o] = 1.0f / (1.0f + __expf(-(sum + b_lin[o])));
}

extern "C" void kernel_launch(void* const* d_in, const int* in_sizes, int n_in,
                              void* d_out, int out_size, void* d_ws, size_t ws_size,
                              hipStream_t stream) {
    const float* X     = (const float*)d_in[0];
    // d_in[1] Mask, d_in[2] Delta, d_in[3] dt: unused by the forward pass
    const float* W_ih  = (const float*)d_in[4];
    const float* W_hh  = (const float*)d_in[5];
    const float* b_ih  = (const float*)d_in[6];
    const float* b_hh  = (const float*)d_in[7];
    const float* W_lin = (const float*)d_in[8];
    const float* b_lin = (const float*)d_in[9];
    float* out = (float*)d_out;

    u64* hbuf = (u64*)d_ws;   // 2 * 1024 * 8B = 16 KiB used

    // init: both parity buffers = {tag=0, h=0.0f} (all zero bytes)
    hipMemsetAsync(hbuf, 0, 2 * H_DIM * sizeof(u64), stream);

    lstm_seq<<<NWG, 256, 0, stream>>>(X, W_ih, W_hh, b_ih, b_hh, hbuf);
    lstm_head<<<1, 256, 0, stream>>>(hbuf, W_lin, b_lin, out);
}